// Round 15
// baseline (467.264 us; speedup 1.0000x reference)
//
#include <hip/hip_runtime.h>
#include <stdint.h>

// Problem dims (fixed by reference)
#define TOKENS 8192
#define DIN    4096
#define DOUT   4096

typedef short bf16x8 __attribute__((ext_vector_type(8)));  // 8 bf16 = 4 VGPRs
typedef float f32x4  __attribute__((ext_vector_type(4)));  // MFMA 16x16 accum
typedef int   i32x4  __attribute__((ext_vector_type(4)));  // NT-loadable int4
typedef float f32x4v __attribute__((ext_vector_type(4)));  // NT-loadable float4

// ---- fp32 -> bf16 round-to-nearest-even (inputs finite) ----
__device__ __forceinline__ unsigned short f2bf(float f) {
    union { float f; unsigned int u; } v; v.f = f;
    return (unsigned short)((v.u + 0x7fffu + ((v.u >> 16) & 1u)) >> 16);
}

// ---- ternary int {-1,0,1} -> bf16 bit pattern (2 selects, no float math) ----
__device__ __forceinline__ unsigned short tern2bf(int v) {
    return v == 0 ? (unsigned short)0u
                  : (v > 0 ? (unsigned short)0x3F80u : (unsigned short)0xBF80u);
}

// ---- async global->LDS, 16B/lane; LDS dest = wave-uniform base + lane*16 ----
__device__ __forceinline__ void gload_lds16(const unsigned short* g, unsigned short* l) {
    __builtin_amdgcn_global_load_lds(
        (const __attribute__((address_space(1))) unsigned int*)g,
        (__attribute__((address_space(3))) unsigned int*)l,
        16, 0, 0);
}

// ================= fused prologue: one kernel, two jobs =================
// R15: W-part transposes ENTIRELY IN REGISTERS (no LDS, no syncthreads).
// Old path had ~8-16-way LDS write conflicts (pitch 264 -> row stride == 4
// mod 32 banks) -- suspected cause of fused_cvt's ~4.5x-over-roofline time.
// Each thread: 8x int4 load (8k x 4n micro-tile; 256B-coalesced per 16 lanes)
// -> register transpose -> 4x uint4 store (64B runs per 4-lane group).
#define WBLKS 1024
#define XBLKS 2048

__global__ __launch_bounds__(256) void fused_cvt(
    const float* __restrict__ x, const int* __restrict__ W,
    unsigned short* __restrict__ xb, unsigned short* __restrict__ Wt) {
    const int t = threadIdx.x;

    if (blockIdx.x < WBLKS) {
        // ---- W transpose: tile k0..k0+255 x n0..n0+63, LDS-free ----
        const int b  = blockIdx.x;
        const int k0 = (b >> 6) * 256;        // 16 k-tiles
        const int n0 = (b & 63) * 64;         // 64 n-tiles
        const int nq = t & 15;                // n-quad (4 n values)
        const int kh = t >> 4;                // 0..15 k-octet index (per it)
#pragma unroll
        for (int it = 0; it < 2; ++it) {
            const int oct = it * 16 + kh;     // k-octet 0..31
            const int kb  = oct * 8;          // k_local base (8 rows)
            i32x4 v[8];
#pragma unroll
            for (int r = 0; r < 8; ++r)
                v[r] = __builtin_nontemporal_load(
                    (const i32x4*)&W[(size_t)(k0 + kb + r) * DOUT + n0 + nq * 4]);
            // register transpose: produce 8 packed bf16 along k for each n
#pragma unroll
            for (int j = 0; j < 4; ++j) {
                int e[8];
                e[0] = v[0][j]; e[1] = v[1][j]; e[2] = v[2][j]; e[3] = v[3][j];
                e[4] = v[4][j]; e[5] = v[5][j]; e[6] = v[6][j]; e[7] = v[7][j];
                uint4 p;
                p.x = (unsigned)tern2bf(e[0]) | ((unsigned)tern2bf(e[1]) << 16);
                p.y = (unsigned)tern2bf(e[2]) | ((unsigned)tern2bf(e[3]) << 16);
                p.z = (unsigned)tern2bf(e[4]) | ((unsigned)tern2bf(e[5]) << 16);
                p.w = (unsigned)tern2bf(e[6]) | ((unsigned)tern2bf(e[7]) << 16);
                *(uint4*)&Wt[(size_t)(n0 + nq * 4 + j) * DIN + k0 + kb] = p;
            }
        }
    } else {
        // ---- x convert part: 8 chunks of 8 floats per thread ----
        const int b2 = blockIdx.x - WBLKS;    // 0..2047
        const int stride = XBLKS * 256;       // chunks per sweep
        int c = b2 * 256 + t;
        const f32x4v* x4 = (const f32x4v*)x;
        uint4* o = (uint4*)xb;                // 8 bf16 = 16B per chunk
#pragma unroll
        for (int j = 0; j < 8; ++j, c += stride) {
            f32x4v a = __builtin_nontemporal_load(&x4[2 * c]);
            f32x4v bvec = __builtin_nontemporal_load(&x4[2 * c + 1]);
            uint4 p;
            p.x = (unsigned)f2bf(a.x)    | ((unsigned)f2bf(a.y) << 16);
            p.y = (unsigned)f2bf(a.z)    | ((unsigned)f2bf(a.w) << 16);
            p.z = (unsigned)f2bf(bvec.x) | ((unsigned)f2bf(bvec.y) << 16);
            p.w = (unsigned)f2bf(bvec.z) | ((unsigned)f2bf(bvec.w) << 16);
            o[c] = p;
        }
    }
}

// ========= main GEMM: 256x256, BK=64, 1-barrier/phase pipeline (R13-verified) =========
// R13 benched 238.8 us (session best); R14's 4-phase merge regressed (243) ->
// reverted verbatim. Phase: [reads (next-phase A-quad; +B-burst at p0/p4)]
// [stage half-tile] [VM2 at p2/p6] BAR LGK4 SB0 setprio(1) 16xMFMA setprio(0)
// Ledger: p0/p1 A@kt+64->sA[1]; p2/p3 B@kt+128->sB[0]; p4/p5 A@kt+128->sA[0];
// p6/p7 B@kt+192->sB[1]. VM2@p2/p6 = cross-wave confirm before next buf reads.
// Never drains vmcnt to 0 in the loop. Plain C stores (L2 write-combining).
#define BM 256
#define BN 256
#define BK 64

#define STAGE_A(bufi, h, kt)                                                \
    do {                                                                    \
        gload_lds16(gA + (size_t)((h) * 128) * DIN + (kt),                  \
                    &sA[bufi][(h) * 8192 + wave * 1024]);                   \
        gload_lds16(gA + (size_t)((h) * 128 + 8) * DIN + (kt),              \
                    &sA[bufi][(h) * 8192 + wave * 1024 + 512]);             \
    } while (0)

#define STAGE_B(bufi, h, kt)                                                \
    do {                                                                    \
        gload_lds16(gB + (size_t)((h) * 128) * DIN + (kt),                  \
                    &sB[bufi][(h) * 8192 + wave * 1024]);                   \
        gload_lds16(gB + (size_t)((h) * 128 + 8) * DIN + (kt),              \
                    &sB[bufi][(h) * 8192 + wave * 1024 + 512]);             \
    } while (0)

#define BAR  __builtin_amdgcn_s_barrier()
#define SB0  __builtin_amdgcn_sched_barrier(0)
#define VM4  asm volatile("s_waitcnt vmcnt(4)" ::: "memory")
#define VM2  asm volatile("s_waitcnt vmcnt(2)" ::: "memory")
#define VM0  asm volatile("s_waitcnt vmcnt(0)" ::: "memory")
#define LGK4 asm volatile("s_waitcnt lgkmcnt(4)" ::: "memory")
#define LGK0 asm volatile("s_waitcnt lgkmcnt(0)" ::: "memory")

// 8 ds_read_b128: all B-frags of LDS buffer BUF (resident across 4 phases)
#define RD_B(BUF)                                                           \
    do {                                                                    \
        _Pragma("unroll") for (int ni = 0; ni < 4; ++ni) {                  \
            bfr[ni][0] = *(const bf16x8*)&sB[BUF][rowB + ni * 1024 + q80];  \
            bfr[ni][1] = *(const bf16x8*)&sB[BUF][rowB + ni * 1024 + q81];  \
        }                                                                   \
    } while (0)

// 4 ds_read_b128: A-frags, quadrant QD of buffer BUF -> register set AF
#define RD_A(AF, BUF, QD)                                                   \
    do {                                                                    \
        _Pragma("unroll") for (int m2 = 0; m2 < 2; ++m2) {                  \
            AF[m2][0] =                                                     \
                *(const bf16x8*)&sA[BUF][rowA + ((QD)*2 + m2) * 1024 + q80];\
            AF[m2][1] =                                                     \
                *(const bf16x8*)&sA[BUF][rowA + ((QD)*2 + m2) * 1024 + q81];\
        }                                                                   \
    } while (0)

// 16 MFMA: quadrant QD from A-set AF + resident bfr
#define MM(AF, QD)                                                          \
    do {                                                                    \
        __builtin_amdgcn_s_setprio(1);                                      \
        _Pragma("unroll") for (int ks = 0; ks < 2; ++ks)                    \
            _Pragma("unroll") for (int m2 = 0; m2 < 2; ++m2)                \
                _Pragma("unroll") for (int ni = 0; ni < 4; ++ni)            \
                    acc[(QD)*2 + m2][ni] =                                  \
                        __builtin_amdgcn_mfma_f32_16x16x32_bf16(            \
                            AF[m2][ks], bfr[ni][ks],                        \
                            acc[(QD)*2 + m2][ni], 0, 0, 0);                 \
        __builtin_amdgcn_s_setprio(0);                                      \
    } while (0)

__global__ __launch_bounds__(512, 2) void gemm_bt(
    const unsigned short* __restrict__ A,   // [M][K] bf16
    const unsigned short* __restrict__ B,   // [N][K] bf16 (W transposed)
    float* __restrict__ C) {                // [M][N] fp32
    const int K = DIN, N = DOUT;

    __shared__ __align__(16) unsigned short sA[2][BM * BK];  // 2 x 32 KB
    __shared__ __align__(16) unsigned short sB[2][BN * BK];  // 2 x 32 KB

    const int tid  = threadIdx.x;
    const int wave = tid >> 6;
    const int lane = tid & 63;
    const int wm = wave >> 2;               // 0..1  (M)
    const int wn = wave & 3;                // 0..3  (N)

    // ---- T1: XCD-aware bijective block swizzle (512 wgs, 8 XCDs, 64/XCD) ----
    const int wg  = blockIdx.x + gridDim.x * blockIdx.y;   // hardware linear id
    const int xcd = wg & 7;
    const int idx = wg >> 3;                               // 0..63 within XCD
    const int bx  = (xcd & 1) * 8 + (idx & 7);             // 0..15  (N tiles)
    const int by  = (xcd >> 1) * 8 + (idx >> 3);           // 0..31  (M tiles)

    // ---- staging addressing: wave w stages rows 16w..16w+15 of each half ----
    const int lrow = lane >> 3;             // 0..7 row within 8-row chunk
    const int qsrc = (lane & 7) ^ lrow;     // pre-swizzled global k-quad
    const unsigned short* gA =
        A + (size_t)(by * BM + wave * 16 + lrow) * K + qsrc * 8;
    const unsigned short* gB =
        B + (size_t)(bx * BN + wave * 16 + lrow) * K + qsrc * 8;

    // ---- fragment read addressing (swizzled ds_read) ----
    const int mrow = lane & 15;
    const int kgrp = lane >> 4;             // 0..3
    const int xr   = lane & 7;              // = row&7 of the frag row
    const int q80  = ((kgrp ^ xr) << 3);        // ks=0 swizzled quad * 8
    const int q81  = (((4 | kgrp) ^ xr) << 3);  // ks=1
    const int rowA = (wm * 128 + mrow) << 6;    // *64 elems/row
    const int rowB = (wn * 64 + mrow) << 6;

    f32x4 acc[8][4];
#pragma unroll
    for (int i = 0; i < 8; ++i)
#pragma unroll
        for (int j = 0; j < 4; ++j) {
            f32x4 z = {0.f, 0.f, 0.f, 0.f};
            acc[i][j] = z;
        }
    bf16x8 bfr[4][2];     // B-frags: resident across a K-tile's 4 phases
    bf16x8 afA[2][2];     // A-frag ping
    bf16x8 afB[2][2];     // A-frag pong

    // ---- prologue: A0, B0, B1 (12 gloads); VM4 confirms A0,B0; B1 flies ----
    STAGE_A(0, 0, 0);
    STAGE_A(0, 1, 0);
    STAGE_B(0, 0, 0);
    STAGE_B(0, 1, 0);
    STAGE_B(1, 0, 64);
    STAGE_B(1, 1, 64);
    VM4;
    BAR;
    RD_A(afA, 0, 0);      // tile0 Q0 (consumed at first p0)

    // ---- main loop: 31 iters (tiles 0..61), 8 phases, 1 barrier each ----
    for (int kt = 0; kt + 256 <= K; kt += 128) {
        // p0: B0-burst (pinned first) + A0Q1 ahead; MFMA Q0(buf0)
        RD_B(0); SB0; RD_A(afB, 0, 1);
        STAGE_A(1, 0, kt + 64);
        BAR; LGK4; SB0; MM(afA, 0);
        // p1
        RD_A(afA, 0, 2);
        STAGE_A(1, 1, kt + 64);
        BAR; LGK4; SB0; MM(afB, 1);
        // p2: VM2 confirms leftover B1 + A@kt+64 before BAR (p3 reads sA[1])
        RD_A(afB, 0, 3);
        STAGE_B(0, 0, kt + 128);
        VM2;
        BAR; LGK4; SB0; MM(afA, 2);
        // p3
        RD_A(afA, 1, 0);
        STAGE_B(0, 1, kt + 128);
        BAR; LGK4; SB0; MM(afB, 3);
        // p4: B1-burst + A1Q1; MFMA Q0(buf1)
        RD_B(1); SB0; RD_A(afB, 1, 1);
        STAGE_A(0, 0, kt + 128);
        BAR; LGK4; SB0; MM(afA, 0);
        // p5
        RD_A(afA, 1, 2);
        STAGE_A(0, 1, kt + 128);
        BAR; LGK4; SB0; MM(afB, 1);
        // p6: VM2 confirms B@kt+128 + A@kt+128 before BAR (p7/next-p0 reads)
        RD_A(afB, 1, 3);
        STAGE_B(1, 0, kt + 192);
        VM2;
        BAR; LGK4; SB0; MM(afA, 2);
        // p7: read next tile0's Q0 from re-staged sA[0]
        RD_A(afA, 0, 0);
        STAGE_B(1, 1, kt + 192);
        BAR; LGK4; SB0; MM(afB, 3);
    }

    // ---- peeled tail: tiles 62 (buf0) and 63 (buf1) ----
    {
        RD_B(0); SB0; RD_A(afB, 0, 1);
        STAGE_A(1, 0, K - 64);
        BAR; LGK4; SB0; MM(afA, 0);

        RD_A(afA, 0, 2);
        STAGE_A(1, 1, K - 64);
        BAR; LGK4; SB0; MM(afB, 1);

        RD_A(afB, 0, 3);
        VM0;              // confirm B63 + A63 fully; no more stages
        BAR; LGK4; SB0; MM(afA, 2);

        RD_A(afA, 1, 0);
        BAR; LGK4; SB0; MM(afB, 3);

        RD_B(1); SB0; RD_A(afB, 1, 1);
        BAR; LGK4; SB0; MM(afA, 0);

        RD_A(afA, 1, 2);
        BAR; LGK4; SB0; MM(afB, 1);

        RD_A(afB, 1, 3);
        BAR; LGK4; SB0; MM(afA, 2);

        LGK0; SB0; MM(afB, 3);
    }

    // ---- epilogue: C/D layout col=lane&15, row=(lane>>4)*4+reg ----
    // Plain stores (R13-verified): L2 write-combines 64B halves into 128B lines.
    float* Cw = C + (size_t)(by * BM + wm * 128 + kgrp * 4) * N
                + (size_t)(bx * BN + wn * 64 + mrow);
#pragma unroll
    for (int mi = 0; mi < 8; ++mi)
#pragma unroll
        for (int ni = 0; ni < 4; ++ni)
#pragma unroll
            for (int r = 0; r < 4; ++r)
                Cw[(size_t)(mi * 16 + r) * N + ni * 16] = acc[mi][ni][r];
}

// ============ safety-net fallback if ws is too small (slow but correct) ============
__global__ void gemm_naive(const float* __restrict__ x, const int* __restrict__ W,
                           float* __restrict__ out) {
    int n = blockIdx.x * blockDim.x + threadIdx.x;
    int t = blockIdx.y;
    const float* xr = x + (size_t)t * DIN;
    float acc = 0.f;
    for (int k = 0; k < DIN; ++k)
        acc += xr[k] * (float)W[(size_t)k * DOUT + n];
    out[(size_t)t * DOUT + n] = acc;
}

extern "C" void kernel_launch(void* const* d_in, const int* in_sizes, int n_in,
                              void* d_out, int out_size, void* d_ws, size_t ws_size,
                              hipStream_t stream) {
    const float* x = (const float*)d_in[0];
    const int*   W = (const int*)d_in[1];
    float* out = (float*)d_out;

    const size_t xb_elems = (size_t)TOKENS * DIN;           // 64 MB bf16
    const size_t wt_elems = (size_t)DIN * DOUT;             // 32 MB bf16
    const size_t need = (xb_elems + wt_elems) * sizeof(unsigned short);

    if (ws_size < need) {   // should not happen; correctness safety net
        dim3 g(DOUT / 256, TOKENS);
        gemm_naive<<<g, 256, 0, stream>>>(x, W, out);
        return;
    }

    unsigned short* xb = (unsigned short*)d_ws;
    unsigned short* Wt = xb + xb_elems;

    fused_cvt<<<WBLKS + XBLKS, 256, 0, stream>>>(x, W, xb, Wt);

    dim3 grid(DOUT / BN, TOKENS / BM);   // (16, 32)
    gemm_bt<<<grid, 512, 0, stream>>>(xb, Wt, out);
}